// Round 2
// baseline (11899.849 us; speedup 1.0000x reference)
//
#include <hip/hip_runtime.h>
#include <cstdint>
#include <cstddef>

typedef unsigned short u16;
typedef unsigned int u32;
typedef __attribute__((ext_vector_type(8))) short bf16x8;  // 8 bf16 (4 VGPRs) — MFMA A/B frag
typedef __attribute__((ext_vector_type(4))) float f32x4;   // MFMA C/D frag

#define T_SEQ 512
#define HID 512

// ---------- dtype helpers ----------
__device__ __forceinline__ u16 f2bf(float f) {
  union { float f; u32 i; } c; c.f = f;
  u32 r = (c.i + 0x7FFFu + ((c.i >> 16) & 1u)) >> 16;  // RNE
  return (u16)r;
}
__device__ __forceinline__ u16 f2h(float f) {
  union { _Float16 h; u16 u; } c; c.h = (_Float16)f; return c.u;
}
__device__ __forceinline__ float h2f(u16 u) {
  union { u16 u; _Float16 h; } c; c.u = u; return (float)c.h;
}
__device__ __forceinline__ float sigmf(float x) { return 1.f / (1.f + __expf(-x)); }
__device__ __forceinline__ float tanhfast(float x) {
  float e = __expf(2.f * x); return 1.f - 2.f / (e + 1.f);  // saturates to ±1
}

// ---------------------------------------------------------------------------
// xg GEMM: xg[dir][m][n] = sum_k A[m][k] * W[dir][n][k] + bias[dir][n]
// A: [8192, K] (fp32 if AF32 else bf16) row-major; W: [1536, K] fp32 row-major.
// out: fp16 [8192,1536]. 128x128 tile, BK=32, 4 waves (2x2), 4x4 16x16x32 MFMA.
// Layouts (HW-verified m89/m120): A frag lane holds A[m=lane&15][k=quad*8+j];
// B frag B[k=quad*8+j][n=lane&15]; D: n=lane&15, m=quad*4+reg.
// ---------------------------------------------------------------------------
template <int AF32>
__launch_bounds__(256)
__global__ void gemm_xg(const void* __restrict__ Av,
                        const float* __restrict__ W0, const float* __restrict__ W1,
                        const float* __restrict__ b0, const float* __restrict__ b1,
                        u16* __restrict__ xg0, u16* __restrict__ xg1, int K) {
  const int dir = blockIdx.z;
  const float* W = dir ? W1 : W0;
  const float* bias = dir ? b1 : b0;
  u16* xg = dir ? xg1 : xg0;
  const int bm = blockIdx.x, bn = blockIdx.y;
  const int tid = threadIdx.x, lane = tid & 63, wv = tid >> 6;
  const int wm = wv & 1, wn = wv >> 1, quad = lane >> 4, l15 = lane & 15;

  __shared__ u16 As[128 * 40];  // +8 pad per 32-elem row -> conflict-free b128 reads
  __shared__ u16 Bs[128 * 40];

  f32x4 acc[4][4] = {};
  const float* Wb = W + (size_t)(bn * 128) * K;

  for (int k0 = 0; k0 < K; k0 += 32) {
    __syncthreads();  // protect LDS from previous iter's readers
    if constexpr (AF32) {
      const float* Ab = (const float*)Av + (size_t)(bm * 128) * K;
#pragma unroll
      for (int it = 0; it < 4; ++it) {
        int c = tid + it * 256;  // 1024 float4 chunks
        int row = c >> 3, kp = (c & 7) * 4;
        float4 v = *(const float4*)(Ab + (size_t)row * K + k0 + kp);
        ushort4 s = { f2bf(v.x), f2bf(v.y), f2bf(v.z), f2bf(v.w) };
        *(ushort4*)(&As[row * 40 + kp]) = s;
      }
    } else {
      const u16* Ab = (const u16*)Av + (size_t)(bm * 128) * K;
#pragma unroll
      for (int it = 0; it < 2; ++it) {
        int c = tid + it * 256;  // 512 chunks of 8 bf16
        int row = c >> 2, kp = (c & 3) * 8;
        *(bf16x8*)(&As[row * 40 + kp]) = *(const bf16x8*)(Ab + (size_t)row * K + k0 + kp);
      }
    }
#pragma unroll
    for (int it = 0; it < 4; ++it) {  // W is always fp32
      int c = tid + it * 256;
      int row = c >> 3, kp = (c & 7) * 4;
      float4 v = *(const float4*)(Wb + (size_t)row * K + k0 + kp);
      ushort4 s = { f2bf(v.x), f2bf(v.y), f2bf(v.z), f2bf(v.w) };
      *(ushort4*)(&Bs[row * 40 + kp]) = s;
    }
    __syncthreads();
    bf16x8 af[4], bf[4];
#pragma unroll
    for (int i = 0; i < 4; ++i) {
      af[i] = *(const bf16x8*)(&As[(wm * 64 + i * 16 + l15) * 40 + quad * 8]);
      bf[i] = *(const bf16x8*)(&Bs[(wn * 64 + i * 16 + l15) * 40 + quad * 8]);
    }
#pragma unroll
    for (int mi = 0; mi < 4; ++mi)
#pragma unroll
      for (int ni = 0; ni < 4; ++ni)
        acc[mi][ni] = __builtin_amdgcn_mfma_f32_16x16x32_bf16(af[mi], bf[ni], acc[mi][ni], 0, 0, 0);
  }

  // epilogue: + bias, store fp16
#pragma unroll
  for (int ni = 0; ni < 4; ++ni) {
    int n = bn * 128 + wn * 64 + ni * 16 + l15;
    float bv = bias[n];
#pragma unroll
    for (int mi = 0; mi < 4; ++mi) {
      int m0 = bm * 128 + wm * 64 + mi * 16 + quad * 4;
#pragma unroll
      for (int r = 0; r < 4; ++r)
        xg[(size_t)(m0 + r) * 1536 + n] = f2h(acc[mi][ni][r] + bv);
    }
  }
}

// ---------------------------------------------------------------------------
// Persistent GRU recurrence. Grid: (8 WGs per direction) x (ndir). 384 thr (6 waves).
// WG w owns hidden units [w*64, w*64+64) => 12 gate tiles (3 gates x 4 j-tiles).
// Each wave keeps 2 tiles of whh register-resident as bf16 B-frags (128 VGPR).
// Cross-WG h exchange via device(agent)-scope atomics through the coherence point
// (per-XCD L2s are NOT coherent — §6 G16); per-step arrive counters with an init
// slot (done[0]=h0 published, done[t+1]=h_t published); xg slice prefetched into
// LDS before the spin. h carried in fp32 LDS; only the exchanged copy is bf16.
// ---------------------------------------------------------------------------
__launch_bounds__(384, 1)
__global__ void gru_rec(const u16* __restrict__ xg_f, const u16* __restrict__ xg_b,
                        const float* __restrict__ whh_f, const float* __restrict__ whh_b,
                        const float* __restrict__ bhh_f, const float* __restrict__ bhh_b,
                        const float* __restrict__ h0_f, const float* __restrict__ h0_b,
                        void* __restrict__ outp, int out_stride, int out_f32,
                        u16* __restrict__ hbuf, int* __restrict__ counters, int Tn) {
  const int dir = blockIdx.y;
  const u16* xg   = dir ? xg_b  : xg_f;
  const float* whh = dir ? whh_b : whh_f;
  const float* bhh = dir ? bhh_b : bhh_f;
  const float* h0  = dir ? h0_b  : h0_f;
  const int w = blockIdx.x;  // 0..7
  const int tid = threadIdx.x, lane = tid & 63, wv = tid >> 6;  // wv 0..5
  const int quad = lane >> 4, l15 = lane & 15;
  int* cnt = counters + dir * 1024;                 // slots [0..Tn]
  u16* hb0 = hbuf + (dir * 2 + 0) * (16 * 512);
  u16* hb1 = hbuf + (dir * 2 + 1) * (16 * 512);
  const int dir_off = dir * 512;

  __shared__ float glds[3][16][64];   // recurrent gate pre-activations
  __shared__ float hprev[16][64];     // this WG's fp32 h slice (exact carry)
  __shared__ u16 xlds[3][16][64];     // fp16 xg slice for current t
  __shared__ float bhl[3][64];        // bhh slice

  // --- register-resident whh B-frags (fp32 -> bf16, once) ---
  bf16x8 bfr[2][16];
#pragma unroll
  for (int f = 0; f < 2; ++f) {
    int fl = wv * 2 + f;              // 0..11
    int g = fl >> 2, q = fl & 3;
    int row = g * 512 + (w * 4 + q) * 16 + l15;
    const float* wp = whh + (size_t)row * 512 + quad * 8;
#pragma unroll
    for (int kt = 0; kt < 16; ++kt) {
      float4 a = *(const float4*)(wp + kt * 32);
      float4 b = *(const float4*)(wp + kt * 32 + 4);
      bf16x8 fr;
      fr[0] = (short)f2bf(a.x); fr[1] = (short)f2bf(a.y);
      fr[2] = (short)f2bf(a.z); fr[3] = (short)f2bf(a.w);
      fr[4] = (short)f2bf(b.x); fr[5] = (short)f2bf(b.y);
      fr[6] = (short)f2bf(b.z); fr[7] = (short)f2bf(b.w);
      bfr[f][kt] = fr;
    }
  }
  // --- init: hprev (fp32) + publish bf16 h0 slice to hb1 ("step -1", parity 1) ---
  for (int i = tid; i < 512; i += 384) {
    int b = i >> 5, j2 = (i & 31) * 2;
    float v0 = h0[b * 512 + w * 64 + j2];
    float v1 = h0[b * 512 + w * 64 + j2 + 1];
    hprev[b][j2] = v0; hprev[b][j2 + 1] = v1;
    u32 pk = (u32)f2bf(v0) | ((u32)f2bf(v1) << 16);
    __hip_atomic_store((u32*)(hb1 + b * 512 + w * 64 + j2), pk,
                       __ATOMIC_RELAXED, __HIP_MEMORY_SCOPE_AGENT);
  }
  for (int i = tid; i < 192; i += 384) {
    int g = i >> 6, jl = i & 63;
    bhl[g][jl] = bhh[g * 512 + w * 64 + jl];
  }
  __syncthreads();  // drains all waves' vmcnt before signal
  if (tid == 0)
    __hip_atomic_fetch_add(&cnt[0], 1, __ATOMIC_RELEASE, __HIP_MEMORY_SCOPE_AGENT);

  for (int t = 0; t < Tn; ++t) {
    const int te = dir ? (Tn - 1 - t) : t;
    // (a) prefetch xg slice for step t into LDS (independent of h -> overlaps spin)
    for (int i = tid; i < 768; i += 384) {  // 768 x uint2 (4 fp16)
      int g = i >> 8, r2 = i & 255, b = r2 >> 4, j4 = (r2 & 15) * 4;
      uint2 v = *(const uint2*)(xg + ((size_t)(b * Tn + te)) * 1536 + g * 512 + w * 64 + j4);
      *(uint2*)(&xlds[g][b][j4]) = v;
    }
    // (b) wait until all 8 WGs have published h for step t
    if (tid == 0) {
      while (__hip_atomic_load(&cnt[t], __ATOMIC_RELAXED, __HIP_MEMORY_SCOPE_AGENT) < 8)
        __builtin_amdgcn_s_sleep(1);
      (void)__hip_atomic_load(&cnt[t], __ATOMIC_ACQUIRE, __HIP_MEMORY_SCOPE_AGENT);
    }
    __syncthreads();

    // (c) A-frags: full 16x512 bf16 h from exchange buffer (LLC-hot, 16KB)
    const u16* hsrc = (t & 1) ? hb0 : hb1;   // step t-1 (or init) wrote parity (t-1)&1
    const u16* hp = hsrc + l15 * 512 + quad * 8;
    bf16x8 afr[16];
#pragma unroll
    for (int kt = 0; kt < 16; ++kt) afr[kt] = *(const bf16x8*)(hp + kt * 32);

    // (d) MFMA: gh tiles -> glds
#pragma unroll
    for (int f = 0; f < 2; ++f) {
      f32x4 acc = {0.f, 0.f, 0.f, 0.f};
#pragma unroll
      for (int kt = 0; kt < 16; ++kt)
        acc = __builtin_amdgcn_mfma_f32_16x16x32_bf16(afr[kt], bfr[f][kt], acc, 0, 0, 0);
      int fl = wv * 2 + f, g = fl >> 2, q = fl & 3;
#pragma unroll
      for (int r = 0; r < 4; ++r) glds[g][quad * 4 + r][q * 16 + l15] = acc[r];
    }
    __syncthreads();

    // (e) gate combine + h update (512 j-pairs)
    u16* hbw = (t & 1) ? hb1 : hb0;          // step t writes parity t&1
    for (int i = tid; i < 512; i += 384) {
      int b = i >> 5, j2 = (i & 31) * 2;
      float hn2[2];
#pragma unroll
      for (int u = 0; u < 2; ++u) {
        int jl = j2 + u;
        float xr = h2f(xlds[0][b][jl]);
        float xz = h2f(xlds[1][b][jl]);
        float xn = h2f(xlds[2][b][jl]);
        float hr = glds[0][b][jl] + bhl[0][jl];
        float hz = glds[1][b][jl] + bhl[1][jl];
        float hnn = glds[2][b][jl] + bhl[2][jl];
        float r = sigmf(xr + hr);
        float z = sigmf(xz + hz);
        float n = tanhfast(xn + r * hnn);
        float hv = (1.f - z) * n + z * hprev[b][jl];
        hprev[b][jl] = hv;
        hn2[u] = hv;
      }
      u32 pk = (u32)f2bf(hn2[0]) | ((u32)f2bf(hn2[1]) << 16);
      __hip_atomic_store((u32*)(hbw + b * 512 + w * 64 + j2), pk,
                         __ATOMIC_RELAXED, __HIP_MEMORY_SCOPE_AGENT);
      if (out_f32) {
        float2 o = { hn2[0], hn2[1] };
        *(float2*)((float*)outp + (size_t)(b * Tn + te) * out_stride + dir_off + w * 64 + j2) = o;
      } else {
        *(u32*)((u16*)outp + (size_t)(b * Tn + te) * out_stride + dir_off + w * 64 + j2) = pk;
      }
    }
    __syncthreads();  // all waves' h stores drained (vmcnt) before signal
    if (tid == 0)
      __hip_atomic_fetch_add(&cnt[t + 1], 1, __ATOMIC_RELEASE, __HIP_MEMORY_SCOPE_AGENT);
  }
}

// ---------------------------------------------------------------------------
// Final FC: d_out[b] = sigmoid(out2[b, T-1, :] . fc_w + fc_b)   (all fp32)
// ---------------------------------------------------------------------------
__global__ void fc_kernel(const float* __restrict__ out2, const float* __restrict__ fc_w,
                          const float* __restrict__ fc_b, float* __restrict__ dst) {
  int b = blockIdx.x, lane = threadIdx.x;  // 64 threads
  const float* row = out2 + ((size_t)b * T_SEQ + (T_SEQ - 1)) * HID;
  float s = 0.f;
  for (int j = lane; j < HID; j += 64) s += row[j] * fc_w[j];
#pragma unroll
  for (int off = 32; off > 0; off >>= 1) s += __shfl_down(s, off, 64);
  if (lane == 0) dst[b] = sigmf(s + fc_b[0]);
}

// ---------------------------------------------------------------------------
// inputs (fp32): 0 x, 1 h1, 2 h2, [3..6]=l0f(wih,whh,bih,bhh), [7..10]=l0b,
// [11..14]=l1f, [15..18]=l1b, [19..22]=l2f, [23..26]=l2b, [27..30]=g2, 31 fc_w, 32 fc_b
// d_out (fp32): 16 sigmoid logits, then out2 [16,512,512].
// ws: xg0 fp16 (8192*1536) | xg1 fp16 | outb bf16 (8192*1024) | hbuf bf16 (4*8192)
//     | counters (8192 int)
// ---------------------------------------------------------------------------
extern "C" void kernel_launch(void* const* d_in, const int* in_sizes, int n_in,
                              void* d_out, int out_size, void* d_ws, size_t ws_size,
                              hipStream_t stream) {
  const float* x  = (const float*)d_in[0];
  const float* h1 = (const float*)d_in[1];
  const float* h2 = (const float*)d_in[2];
  auto P = [&](int i) { return (const float*)d_in[i]; };

  u16* xg0 = (u16*)d_ws;
  u16* xg1 = xg0 + (size_t)8192 * 1536;
  u16* outb = xg1 + (size_t)8192 * 1536;
  u16* hbuf = outb + (size_t)8192 * 1024;
  int* counters = (int*)(hbuf + 4 * 8192);
  float* out_f = (float*)d_out;
  float* out2 = out_f + 16;

  hipMemsetAsync(counters, 0, 8192 * sizeof(int), stream);

  // layer 0 (A = x fp32, K=2048)
  gemm_xg<1><<<dim3(64, 12, 2), 256, 0, stream>>>(x, P(3), P(7), P(5), P(9), xg0, xg1, 2048);
  gru_rec<<<dim3(8, 2), 384, 0, stream>>>(xg0, xg1, P(4), P(8), P(6), P(10),
                                          h1, h1 + 8192, outb, 1024, 0, hbuf, counters, T_SEQ);
  // layer 1 (A = outb bf16, K=1024)
  gemm_xg<0><<<dim3(64, 12, 2), 256, 0, stream>>>(outb, P(11), P(15), P(13), P(17), xg0, xg1, 1024);
  gru_rec<<<dim3(8, 2), 384, 0, stream>>>(xg0, xg1, P(12), P(16), P(14), P(18),
                                          h1 + 2 * 8192, h1 + 3 * 8192, outb, 1024, 0, hbuf,
                                          counters + 2048, T_SEQ);
  // layer 2 (K=1024)
  gemm_xg<0><<<dim3(64, 12, 2), 256, 0, stream>>>(outb, P(19), P(23), P(21), P(25), xg0, xg1, 1024);
  gru_rec<<<dim3(8, 2), 384, 0, stream>>>(xg0, xg1, P(20), P(24), P(22), P(26),
                                          h1 + 4 * 8192, h1 + 5 * 8192, outb, 1024, 0, hbuf,
                                          counters + 4096, T_SEQ);
  // g2 (unidirectional, K=1024) -> writes out2 region of d_out (fp32)
  gemm_xg<0><<<dim3(64, 12, 1), 256, 0, stream>>>(outb, P(27), P(27), P(29), P(29), xg0, xg1, 1024);
  gru_rec<<<dim3(8, 1), 384, 0, stream>>>(xg0, xg0, P(28), P(28), P(30), P(30),
                                          h2, h2, out2, 512, 1, hbuf, counters + 6144, T_SEQ);
  fc_kernel<<<16, 64, 0, stream>>>(out2, P(31), P(32), out_f);
}